// Round 6
// baseline (179.764 us; speedup 1.0000x reference)
//
#include <hip/hip_runtime.h>
#include <math.h>

#define CH 512
#define CQ 64
#define HH 64
#define WW 64
#define PP (HH*WW)   // 4096
#define BB 8

typedef __bf16 bf16x8 __attribute__((ext_vector_type(8)));
typedef __bf16 bf16x4 __attribute__((ext_vector_type(4)));
typedef float  f32x4  __attribute__((ext_vector_type(4)));

// ---- LDS helpers (inline asm; keep asm ds ops and compiler ds ops in
// ---- disjoint regions, one lgkmcnt(0)+sched_barrier(0) before MFMAs) ----
__device__ __forceinline__ unsigned lds_off(const void* p) {
  return (unsigned)(size_t)(__attribute__((address_space(3))) const void*)p;
}
__device__ __forceinline__ bf16x4 ds_tr16(unsigned addr) {
  bf16x4 r;
  asm volatile("ds_read_b64_tr_b16 %0, %1" : "=v"(r) : "v"(addr));
  return r;
}

// ---------------------------------------------------------------------------
// proj_mfma: Y[m, o] = sum_c X[b, c, p] * W[o, c] + bias[o],  m = b*4096 + p
// bf16 MFMA 16x16x32. Two input sets, selected by blockIdx.z (q/k fusion).
// SPLIT: hi+lo bf16 decomposition (3 MFMAs) for ~f32 accuracy.
// DBUF: double-buffered LDS (1 barrier/step) vs single (2 barriers/step).
// Wave grid WGM x WGN, wave tile (FM*16) x (FN*16).
// ---------------------------------------------------------------------------
template<int TPB, int WGM, int WGN, int FM, int FN, bool SPLIT, bool DBUF,
         int NOUT, typename OutT>
__global__ __launch_bounds__(TPB) void proj_mfma_kernel(
    const float* __restrict__ X0, const float* __restrict__ W0,
    const float* __restrict__ bias0, OutT* __restrict__ Y0,
    const float* __restrict__ X1, const float* __restrict__ W1,
    const float* __restrict__ bias1, OutT* __restrict__ Y1)
{
  constexpr int BM = WGM * FM * 16;
  constexpr int BN = WGN * FN * 16;
  constexpr int NS = SPLIT ? 2 : 1;
  constexpr int NBUF = DBUF ? 2 : 1;
  constexpr int NA = (BM * 8) / TPB;   // 4-elem A chunks per thread
  constexpr int NB = (BN * 8) / TPB;   // 4-elem B chunks per thread
  __shared__ __align__(16) __bf16 As[NBUF][NS][BM][40];
  __shared__ __align__(16) __bf16 Bs[NBUF][NS][BN][40];

  const int tid = threadIdx.x;
  const int sel = blockIdx.z;
  const float* X    = sel ? X1 : X0;
  const float* W    = sel ? W1 : W0;
  const float* bias = sel ? bias1 : bias0;
  OutT* Y           = sel ? Y1 : Y0;

  const int mblk = blockIdx.x * BM;
  const int nblk = blockIdx.y * BN;
  const int b     = mblk >> 12;             // batch (BM divides 4096)
  const int pbase = mblk & 4095;
  const float* Xb = X + (size_t)b * CH * PP;

  const int l  = tid & 63;
  const int wv = tid >> 6;
  const int wr = wv / WGN, wc = wv % WGN;
  const int lm = l & 15, lk = l >> 4;

  int ma[NA], ka[NA];
  #pragma unroll
  for (int i = 0; i < NA; ++i) {
    int id = tid + i * TPB;
    ma[i] = id % BM;
    ka[i] = (id / BM) * 4;
  }
  int nb_[NB], kb_[NB];
  #pragma unroll
  for (int i = 0; i < NB; ++i) {
    int id = tid + i * TPB;
    nb_[i] = id % BN;
    kb_[i] = (id / BN) * 4;
  }

  float  ra[NA][4];
  float4 rb[NB];

  auto loadA = [&](int c0) {
    #pragma unroll
    for (int i = 0; i < NA; ++i)
      #pragma unroll
      for (int jj = 0; jj < 4; ++jj)
        ra[i][jj] = Xb[(size_t)(c0 + ka[i] + jj) * PP + pbase + ma[i]];
  };
  auto loadB = [&](int c0) {
    #pragma unroll
    for (int i = 0; i < NB; ++i)
      rb[i] = *(const float4*)(W + (size_t)(nblk + nb_[i]) * CH + c0 + kb_[i]);
  };
  auto stage = [&](int par) {
    #pragma unroll
    for (int i = 0; i < NA; ++i) {
      bf16x4 hv, lv;
      #pragma unroll
      for (int jj = 0; jj < 4; ++jj) {
        __bf16 hh = (__bf16)ra[i][jj];
        hv[jj] = hh;
        if (SPLIT) lv[jj] = (__bf16)(ra[i][jj] - (float)hh);
      }
      *(bf16x4*)&As[par][0][ma[i]][ka[i]] = hv;
      if (SPLIT) *(bf16x4*)&As[par][1][ma[i]][ka[i]] = lv;
    }
    #pragma unroll
    for (int i = 0; i < NB; ++i) {
      float xs[4] = {rb[i].x, rb[i].y, rb[i].z, rb[i].w};
      bf16x4 hv, lv;
      #pragma unroll
      for (int jj = 0; jj < 4; ++jj) {
        __bf16 hh = (__bf16)xs[jj];
        hv[jj] = hh;
        if (SPLIT) lv[jj] = (__bf16)(xs[jj] - (float)hh);
      }
      *(bf16x4*)&Bs[par][0][nb_[i]][kb_[i]] = hv;
      if (SPLIT) *(bf16x4*)&Bs[par][1][nb_[i]][kb_[i]] = lv;
    }
  };

  f32x4 acc[FM][FN];
  #pragma unroll
  for (int j = 0; j < FN; ++j) {
    float bvj = bias[nblk + wc*FN*16 + j*16 + lm];
    #pragma unroll
    for (int i = 0; i < FM; ++i) {
      acc[i][j][0] = bvj; acc[i][j][1] = bvj;
      acc[i][j][2] = bvj; acc[i][j][3] = bvj;
    }
  }

  loadA(0); loadB(0);
  for (int t = 0; t < 16; ++t) {
    const int par = DBUF ? (t & 1) : 0;
    if (!DBUF && t) __syncthreads();   // WAR: prev frag reads done
    stage(par);
    __syncthreads();
    if (t < 15) { loadA((t+1)*32); loadB((t+1)*32); }
    bf16x8 af[NS][FM], bfr[NS][FN];
    #pragma unroll
    for (int s = 0; s < NS; ++s) {
      #pragma unroll
      for (int i = 0; i < FM; ++i)
        af[s][i] = *(const bf16x8*)&As[par][s][wr*FM*16 + i*16 + lm][lk*8];
      #pragma unroll
      for (int j = 0; j < FN; ++j)
        bfr[s][j] = *(const bf16x8*)&Bs[par][s][wc*FN*16 + j*16 + lm][lk*8];
    }
    #pragma unroll
    for (int i = 0; i < FM; ++i) {
      #pragma unroll
      for (int j = 0; j < FN; ++j) {
        acc[i][j] = __builtin_amdgcn_mfma_f32_16x16x32_bf16(
            af[0][i], bfr[0][j], acc[i][j], 0, 0, 0);
        if (SPLIT) {
          acc[i][j] = __builtin_amdgcn_mfma_f32_16x16x32_bf16(
              af[0][i], bfr[1][j], acc[i][j], 0, 0, 0);
          acc[i][j] = __builtin_amdgcn_mfma_f32_16x16x32_bf16(
              af[1][i], bfr[0][j], acc[i][j], 0, 0, 0);
        }
      }
    }
  }
  // epilogue: C/D layout col=lane&15, row=(lane>>4)*4+r
  #pragma unroll
  for (int i = 0; i < FM; ++i) {
    #pragma unroll
    for (int j = 0; j < FN; ++j) {
      #pragma unroll
      for (int r = 0; r < 4; ++r) {
        int mg = mblk + wr*FM*16 + i*16 + lk*4 + r;
        int ng = nblk + wc*FN*16 + j*16 + lm;
        Y[(size_t)mg * NOUT + ng] = (OutT)acc[i][j][r];
      }
    }
  }
}

// ---------------------------------------------------------------------------
// energyH: att[b,h,w,g] = masked q.k with -inf diagonal. grid (W,B), 256.
// ---------------------------------------------------------------------------
__global__ __launch_bounds__(256) void energyH_kernel(
    const float* __restrict__ qt, const float* __restrict__ kt,
    float* __restrict__ att, const int* __restrict__ len_p)
{
  const int tid = threadIdx.x;
  const int w = blockIdx.x, b = blockIdx.y;
  int L = *len_p; L = L < 0 ? 0 : (L > 64 ? 64 : L);
  __shared__ float Qs[64][68];
  __shared__ float Ks[64][68];
  {
    const int c = tid & 63, hg = tid >> 6;
    const float* qb = qt + ((size_t)b * PP + w) * CQ + c;
    const float* kb = kt + ((size_t)b * PP + w) * CQ + c;
    #pragma unroll
    for (int r = 0; r < 16; ++r) {
      int h = hg*16 + r;
      Qs[h][c] = qb[(size_t)h * WW * CQ];
      Ks[h][c] = kb[(size_t)h * WW * CQ];
    }
  }
  __syncthreads();
  const int g  = tid & 63;
  const int wg = tid >> 6;
  float kreg[64];
  #pragma unroll
  for (int c = 0; c < 64; ++c) kreg[c] = (c < L) ? Ks[g][c] : 0.0f;
  const bool gok = (g < L);
  float* ab = att + (((size_t)b * HH) * WW + w) * 128 + g;
  for (int r = 0; r < 16; ++r) {
    int h = wg*16 + r;
    float e = 0.0f;
    #pragma unroll
    for (int c4 = 0; c4 < 16; ++c4) {
      float4 q4 = *(const float4*)&Qs[h][4*c4];
      e += q4.x*kreg[4*c4+0] + q4.y*kreg[4*c4+1]
         + q4.z*kreg[4*c4+2] + q4.w*kreg[4*c4+3];
    }
    e = (gok && h < L) ? e : 0.0f;
    if (g == h) e = -INFINITY;
    ab[(size_t)h * WW * 128] = e;
  }
}

// ---------------------------------------------------------------------------
// energyW + softmax over [eH | eW].  grid (H, B), block 256.
// ---------------------------------------------------------------------------
__global__ __launch_bounds__(256) void energyW_softmax_kernel(
    const float* __restrict__ qt, const float* __restrict__ kt,
    float* __restrict__ att, const int* __restrict__ len_p)
{
  const int tid = threadIdx.x;
  const int h = blockIdx.x, b = blockIdx.y;
  int L = *len_p; L = L < 0 ? 0 : (L > 64 ? 64 : L);
  __shared__ float Qs[64][68];
  __shared__ float Ks[64][68];
  {
    const int c = tid & 63, wg2 = tid >> 6;
    const float* qb = qt + ((size_t)b * PP + (size_t)h * WW) * CQ + c;
    const float* kb = kt + ((size_t)b * PP + (size_t)h * WW) * CQ + c;
    #pragma unroll
    for (int r = 0; r < 16; ++r) {
      int w = wg2*16 + r;
      Qs[w][c] = qb[(size_t)w * CQ];
      Ks[w][c] = kb[(size_t)w * CQ];
    }
  }
  __syncthreads();
  const int g  = tid & 63;
  const int wg = tid >> 6;
  float kreg[64];
  #pragma unroll
  for (int c = 0; c < 64; ++c) kreg[c] = (c < L) ? Ks[g][c] : 0.0f;
  const bool gok = (g < L);
  float* ab = att + (((size_t)b * HH + h) * WW) * 128 + g;
  for (int r = 0; r < 16; ++r) {
    int w = wg*16 + r;
    float e = 0.0f;
    #pragma unroll
    for (int c4 = 0; c4 < 16; ++c4) {
      float4 q4 = *(const float4*)&Qs[w][4*c4];
      e += q4.x*kreg[4*c4+0] + q4.y*kreg[4*c4+1]
         + q4.z*kreg[4*c4+2] + q4.w*kreg[4*c4+3];
    }
    e = (gok && w < L) ? e : 0.0f;
    float eh = ab[(size_t)w * 128];
    float m = fmaxf(e, eh);
    #pragma unroll
    for (int d = 32; d > 0; d >>= 1) m = fmaxf(m, __shfl_xor(m, d, 64));
    float pe = __expf(e  - m);
    float ph = __expf(eh - m);
    float s = pe + ph;
    #pragma unroll
    for (int d = 32; d > 0; d >>= 1) s += __shfl_xor(s, d, 64);
    float inv = 1.0f / s;
    ab[(size_t)w * 128]      = ph * inv;   // attH
    ab[(size_t)w * 128 + 64] = pe * inv;   // attW
  }
}

// ---------------------------------------------------------------------------
// V-tile staging into 16x16-subtiled LDS with j-permutation so that
// ds_read_b64_tr_b16 (lane addr = block_base + 8*l) yields B-fragments:
//   block (s,p): j = s*32 + 8*lk + 4*p + r  stored at row t = 4*lk + r
//   subtile element (j,c): off = ((s*2+p)*8 + (c>>4))*256 + t*16 + (c&15)
// ---------------------------------------------------------------------------
__device__ __forceinline__ int vsub_off(int j, int c0) {
  int s  = j >> 5;
  int p  = (j >> 2) & 1;
  int t  = ((j & 31) >> 3) * 4 + (j & 3);
  return ((s*2 + p)*8 + (c0 >> 4))*256 + t*16 + (c0 & 15);
}

// ---------------------------------------------------------------------------
// outH (MFMA): per (b,w,ct): oH[b,h,w, ct*128+c'] = sum_j attH[h,j]*v[j*64+w,c]
// grid (W, 4, B), block 256 (4 waves; wave wv owns h rows wv*16..+15).
// ---------------------------------------------------------------------------
__global__ __launch_bounds__(256) void outH_mfma_kernel(
    const float* __restrict__ att, const __bf16* __restrict__ vt,
    __bf16* __restrict__ oH)
{
  const int tid = threadIdx.x;
  const int w = blockIdx.x, ct = blockIdx.y, b = blockIdx.z;
  const int l = tid & 63, wv = tid >> 6;
  const int lm = l & 15, lk = l >> 4;

  __shared__ __align__(16) __bf16 Bs[8192];

  #pragma unroll
  for (int i = 0; i < 4; ++i) {
    int j  = i*16 + (tid >> 4);
    int c0 = (tid & 15) * 8;
    bf16x8 v8 = *(const bf16x8*)(vt + ((size_t)b*PP + (size_t)j*WW + w)*CH + ct*128 + c0);
    *(bf16x8*)&Bs[vsub_off(j, c0)] = v8;
  }

  const int hrow = wv*16 + lm;
  const float* ab = att + (((size_t)b*HH + hrow)*WW + w)*128;
  bf16x8 af[2];
  #pragma unroll
  for (int s = 0; s < 2; ++s) {
    float4 a0 = *(const float4*)(ab + s*32 + lk*8);
    float4 a1 = *(const float4*)(ab + s*32 + lk*8 + 4);
    af[s][0]=(__bf16)a0.x; af[s][1]=(__bf16)a0.y; af[s][2]=(__bf16)a0.z; af[s][3]=(__bf16)a0.w;
    af[s][4]=(__bf16)a1.x; af[s][5]=(__bf16)a1.y; af[s][6]=(__bf16)a1.z; af[s][7]=(__bf16)a1.w;
  }
  __syncthreads();

  const unsigned bs_base = lds_off(&Bs[0]);
  f32x4 acc[8];
  #pragma unroll
  for (int f = 0; f < 8; ++f) acc[f] = (f32x4){0.f,0.f,0.f,0.f};
  #pragma unroll
  for (int s = 0; s < 2; ++s) {
    bf16x8 bfr[8];
    #pragma unroll
    for (int f = 0; f < 8; ++f) {
      unsigned base = bs_base + (unsigned)(((s*2)*8 + f)*512) + (unsigned)(l*8);
      bf16x4 t0 = ds_tr16(base);
      bf16x4 t1 = ds_tr16(base + 8*512);   // p=1 block
      bfr[f] = __builtin_shufflevector(t0, t1, 0,1,2,3,4,5,6,7);
    }
    asm volatile("s_waitcnt lgkmcnt(0)");
    __builtin_amdgcn_sched_barrier(0);
    #pragma unroll
    for (int f = 0; f < 8; ++f)
      acc[f] = __builtin_amdgcn_mfma_f32_16x16x32_bf16(af[s], bfr[f], acc[f], 0,0,0);
  }
  __bf16* ob = oH + (((size_t)b * HH) * WW + w) * CH + ct*128;
  #pragma unroll
  for (int f = 0; f < 8; ++f) {
    #pragma unroll
    for (int r = 0; r < 4; ++r) {
      int h = wv*16 + lk*4 + r;
      ob[(size_t)h * WW * CH + f*16 + lm] = (__bf16)acc[f][r];
    }
  }
}

// ---------------------------------------------------------------------------
// outW (MFMA) + final: per (b,h,ct): out = gamma*(outW + oH) + x1
// grid (H, 4, B), block 256. LDS union: Bs (16KB) then Sc halves (17.7KB).
// ---------------------------------------------------------------------------
__global__ __launch_bounds__(256) void outW_final_kernel(
    const float* __restrict__ att, const __bf16* __restrict__ vt,
    const __bf16* __restrict__ oH,
    const float* __restrict__ x1, const float* __restrict__ gamma_p,
    float* __restrict__ out)
{
  const int tid = threadIdx.x;
  const int h = blockIdx.x, ct = blockIdx.y, b = blockIdx.z;
  const int l = tid & 63, wv = tid >> 6;
  const int lm = l & 15, lk = l >> 4;
  const float gamma = *gamma_p;

  __shared__ __align__(16) char smem[64*69*4];   // 17664 B
  __bf16* Bs = (__bf16*)smem;                    // 8192 entries
  typedef float ScRow[69];
  ScRow* Sc = (ScRow*)smem;                      // [64][69] f32

  #pragma unroll
  for (int i = 0; i < 4; ++i) {
    int j  = i*16 + (tid >> 4);
    int c0 = (tid & 15) * 8;
    bf16x8 v8 = *(const bf16x8*)(vt + ((size_t)b*PP + (size_t)h*WW + j)*CH + ct*128 + c0);
    *(bf16x8*)&Bs[vsub_off(j, c0)] = v8;
  }

  const int wrow = wv*16 + lm;
  const float* ab = att + (((size_t)b*HH + h)*WW + wrow)*128 + 64;
  bf16x8 af[2];
  #pragma unroll
  for (int s = 0; s < 2; ++s) {
    float4 a0 = *(const float4*)(ab + s*32 + lk*8);
    float4 a1 = *(const float4*)(ab + s*32 + lk*8 + 4);
    af[s][0]=(__bf16)a0.x; af[s][1]=(__bf16)a0.y; af[s][2]=(__bf16)a0.z; af[s][3]=(__bf16)a0.w;
    af[s][4]=(__bf16)a1.x; af[s][5]=(__bf16)a1.y; af[s][6]=(__bf16)a1.z; af[s][7]=(__bf16)a1.w;
  }
  __syncthreads();

  const unsigned bs_base = lds_off(&Bs[0]);
  f32x4 acc[8];
  #pragma unroll
  for (int f = 0; f < 8; ++f) acc[f] = (f32x4){0.f,0.f,0.f,0.f};
  #pragma unroll
  for (int s = 0; s < 2; ++s) {
    bf16x8 bfr[8];
    #pragma unroll
    for (int f = 0; f < 8; ++f) {
      unsigned base = bs_base + (unsigned)(((s*2)*8 + f)*512) + (unsigned)(l*8);
      bf16x4 t0 = ds_tr16(base);
      bf16x4 t1 = ds_tr16(base + 8*512);
      bfr[f] = __builtin_shufflevector(t0, t1, 0,1,2,3,4,5,6,7);
    }
    asm volatile("s_waitcnt lgkmcnt(0)");
    __builtin_amdgcn_sched_barrier(0);
    #pragma unroll
    for (int f = 0; f < 8; ++f)
      acc[f] = __builtin_amdgcn_mfma_f32_16x16x32_bf16(af[s], bfr[f], acc[f], 0,0,0);
  }

  const __bf16* ohb = oH + (((size_t)b*HH + h) * WW) * CH + ct*128;
  #pragma unroll
  for (int hf = 0; hf < 2; ++hf) {
    __syncthreads();
    #pragma unroll
    for (int f2 = 0; f2 < 4; ++f2) {
      int f = hf*4 + f2;
      #pragma unroll
      for (int r = 0; r < 4; ++r)
        Sc[wv*16 + lk*4 + r][f2*16 + lm] = acc[f][r];
    }
    __syncthreads();
    {
      int w_ = tid >> 2, q = tid & 3;
      #pragma unroll
      for (int e = 0; e < 2; ++e) {
        int cl = q*16 + e*8;
        bf16x8 o8 = *(const bf16x8*)(ohb + (size_t)w_ * CH + hf*64 + cl);
        #pragma unroll
        for (int jj = 0; jj < 8; ++jj)
          Sc[w_][cl + jj] += (float)o8[jj];
      }
    }
    __syncthreads();
    {
      int wl = tid & 63, cg = tid >> 6;
      const float* x1b = x1 + ((size_t)b*CH + ct*128 + hf*64)*PP + (size_t)h*WW + wl;
      float*       obp = out + ((size_t)b*CH + ct*128 + hf*64)*PP + (size_t)h*WW + wl;
      #pragma unroll
      for (int r2 = 0; r2 < 16; ++r2) {
        int ci = cg*16 + r2;
        obp[(size_t)ci * PP] = gamma * Sc[wl][ci] + x1b[(size_t)ci * PP];
      }
    }
  }
}

// ---------------------------------------------------------------------------
extern "C" void kernel_launch(void* const* d_in, const int* in_sizes, int n_in,
                              void* d_out, int out_size, void* d_ws, size_t ws_size,
                              hipStream_t stream)
{
  const float* x1 = (const float*)d_in[0];
  const float* x2 = (const float*)d_in[1];
  const float* x3 = (const float*)d_in[2];
  const float* Wq = (const float*)d_in[3];
  const float* bq = (const float*)d_in[4];
  const float* Wk = (const float*)d_in[5];
  const float* bk = (const float*)d_in[6];
  const float* Wv = (const float*)d_in[7];
  const float* bv = (const float*)d_in[8];
  const float* gamma = (const float*)d_in[9];
  const int*   len   = (const int*)d_in[10];
  float* out = (float*)d_out;

  // workspace layout (96 MiB total):
  float*  q_t = (float*)d_ws;                            // (B,P,64)  f32   8 MiB
  float*  k_t = q_t + (size_t)BB * PP * CQ;              // (B,P,64)  f32   8 MiB
  float*  att = k_t + (size_t)BB * PP * CQ;              // (B,H,W,128) f32 16 MiB
  __bf16* v_t = (__bf16*)(att + (size_t)BB * PP * 128);  // (B,P,512) bf16 32 MiB
  __bf16* oH  = v_t + (size_t)BB * PP * CH;              // (B,H,W,512) bf16 32 MiB

  // v: 512 thr, wave grid 2x4, wave tile 64x32 -> block 128x128, dbuf
  proj_mfma_kernel<512, 2,4, 4,2, false, true, CH, __bf16>
      <<<dim3(BB*PP/128, CH/128, 1), dim3(512), 0, stream>>>(
          x3, Wv, bv, v_t,  x3, Wv, bv, v_t);
  // q+k fused: 512 thr, wave grid 2x4, wave tile 32x16 -> block 64x64,
  // split-bf16, single-buffer; z selects (x1,Wq)->q_t vs (x2,Wk)->k_t
  proj_mfma_kernel<512, 2,4, 2,1, true, false, CQ, float>
      <<<dim3(BB*PP/64, 1, 2), dim3(512), 0, stream>>>(
          x1, Wq, bq, q_t,  x2, Wk, bk, k_t);

  dim3 blk(256);
  energyH_kernel<<<dim3(WW, BB), blk, 0, stream>>>(q_t, k_t, att, len);
  energyW_softmax_kernel<<<dim3(HH, BB), blk, 0, stream>>>(q_t, k_t, att, len);
  outH_mfma_kernel<<<dim3(WW, 4, BB), blk, 0, stream>>>(att, v_t, oH);
  outW_final_kernel<<<dim3(HH, 4, BB), blk, 0, stream>>>(att, v_t, oH, x1, gamma, out);
}